// Round 7
// baseline (3275.705 us; speedup 1.0000x reference)
//
#include <hip/hip_runtime.h>
#include <stdint.h>

#define NN 100000   // nodes
#define NE 400000   // edges before self loops
#define NT 500000   // NE + NN
#define DA 98       // atom feature dim
#define DB 13       // bond feature dim
#define EMB 128
#define HE 512      // HEADS * EMB

typedef unsigned short ushort_t;
typedef __bf16 bf16x8 __attribute__((ext_vector_type(8)));
typedef float floatx4 __attribute__((ext_vector_type(4)));

__device__ __forceinline__ float prelu_f(float x, float a) { return x >= 0.f ? x : a * x; }

__device__ __forceinline__ ushort_t f2bf(float f) {
    unsigned u = __float_as_uint(f);
    unsigned r = (u + 0x7fffu + ((u >> 16) & 1u)) >> 16;  // RNE
    return (ushort_t)r;
}
__device__ __forceinline__ float bflo(unsigned u) { return __uint_as_float(u << 16); }
__device__ __forceinline__ float bfhi(unsigned u) { return __uint_as_float(u & 0xffff0000u); }

// ----------------- src-CSR build (edge_index is int32; softmax groups by src)
__global__ void k_count(const int* __restrict__ ei, int* __restrict__ sc) {
    int e = blockIdx.x * 256 + threadIdx.x;
    if (e >= NT) return;
    int s = (e < NE) ? ei[e] : e - NE;
    atomicAdd(sc + s, 1);
}

__global__ void k_scan1(const int* __restrict__ cnt, int* __restrict__ part, int* __restrict__ bsum) {
    __shared__ int tmp[512];
    int t = threadIdx.x, i = blockIdx.x * 512 + t;
    int v = (i < NN) ? cnt[i] : 0;
    tmp[t] = v;
    __syncthreads();
    for (int off = 1; off < 512; off <<= 1) {
        int x = (t >= off) ? tmp[t - off] : 0;
        __syncthreads();
        tmp[t] += x;
        __syncthreads();
    }
    if (i < NN) part[i] = tmp[t] - v;
    if (t == 511) bsum[blockIdx.x] = tmp[t];
}

__global__ void k_scan2(int* __restrict__ bsum, int nb) {
    __shared__ int tmp[256];
    int t = threadIdx.x;
    int v = (t < nb) ? bsum[t] : 0;
    tmp[t] = v;
    __syncthreads();
    for (int off = 1; off < 256; off <<= 1) {
        int x = (t >= off) ? tmp[t - off] : 0;
        __syncthreads();
        tmp[t] += x;
        __syncthreads();
    }
    if (t < nb) bsum[t] = tmp[t] - v;
}

__global__ void k_scan3(const int* __restrict__ part, const int* __restrict__ bsum,
                        int* __restrict__ off, int* __restrict__ cur) {
    int i = blockIdx.x * 256 + threadIdx.x;
    if (i < NN) {
        int v = part[i] + bsum[i >> 9];
        off[i] = v;
        cur[i] = v;
    }
    if (i == 0) off[NN] = NT;
}

__global__ void k_fill(const int* __restrict__ ei, int* __restrict__ scur, int* __restrict__ seid) {
    int e = blockIdx.x * 256 + threadIdx.x;
    if (e >= NT) return;
    int s = (e < NE) ? ei[e] : e - NE;
    seid[atomicAdd(scur + s, 1)] = e;
}

// ----------------- input embedding: h(bf16) = prelu(x @ x_emb_W) -------------
__global__ __launch_bounds__(128) void k_embed(const float* __restrict__ x, const float* __restrict__ W,
                                               const float* __restrict__ pg, ushort_t* __restrict__ hb) {
    __shared__ float Ws[DA * EMB];   // 50 KB
    __shared__ float xr[DA];
    int t = threadIdx.x;
    for (int i = t; i < DA * EMB; i += 128) Ws[i] = W[i];
    float p = pg[0];
    __syncthreads();
    for (int n = blockIdx.x; n < NN; n += gridDim.x) {
        if (t < DA) xr[t] = x[(size_t)n * DA + t];
        __syncthreads();
        float acc = 0.f;
        #pragma unroll
        for (int k = 0; k < DA; ++k) acc += xr[k] * Ws[k * EMB + t];
        hb[(size_t)n * EMB + t] = f2bf(prelu_f(acc, p));
        __syncthreads();
    }
}

// ----------------- W prep: Wtg[l][n][k] bf16 = wl_W[l][k][n] -----------------
__global__ void k_prep(const float* __restrict__ wlW, ushort_t* __restrict__ Wtg) {
    int idx = blockIdx.x * 256 + threadIdx.x;   // 4*512*128
    if (idx >= 4 * 512 * 128) return;
    int k = idx & 127;
    int n = (idx >> 7) & 511;
    int l = idx >> 16;
    Wtg[idx] = f2bf(wlW[(size_t)l * 65536 + k * 512 + n]);
}

// ----------------- ee_W prep: bf16 copy, same [l][k][ch] layout --------------
__global__ void k_prep_ee(const float* __restrict__ eeW, ushort_t* __restrict__ eeWb) {
    int idx = blockIdx.x * 256 + threadIdx.x;   // 4*13*512
    if (idx >= 4 * DB * HE) return;
    eeWb[idx] = f2bf(eeW[idx]);
}

// ----------------- per-layer GEMM via MFMA: xw = prelu(h @ Wl + bl) ----------
__global__ __launch_bounds__(256) void k_gemm(const ushort_t* __restrict__ hb, const ushort_t* __restrict__ Wtg,
                                              const float* __restrict__ bl, const float* __restrict__ pa,
                                              ushort_t* __restrict__ xw) {
    __shared__ ushort_t At[64 * 136];    // 17.4 KB
    __shared__ ushort_t Bt[128 * 136];   // 34.8 KB
    int t = threadIdx.x;
    int m0 = blockIdx.x * 64;
    int n0 = blockIdx.y * 128;
    for (int idx = t; idx < 64 * 16; idx += 256) {
        int r = idx >> 4, co = (idx & 15) * 8;
        int gr = m0 + r; if (gr >= NN) gr = 0;
        *(uint4*)&At[r * 136 + co] = *(const uint4*)&hb[(size_t)gr * EMB + co];
    }
    for (int idx = t; idx < 128 * 16; idx += 256) {
        int n = idx >> 4, ko = (idx & 15) * 8;
        *(uint4*)&Bt[n * 136 + ko] = *(const uint4*)&Wtg[(size_t)(n0 + n) * 128 + ko];
    }
    float a = pa[0];
    __syncthreads();

    int wv = t >> 6, lane = t & 63;
    int ml = lane & 15, kq = lane >> 4;
    int n0w = wv * 32;
    floatx4 acc[4][2];
    #pragma unroll
    for (int mt = 0; mt < 4; ++mt)
        #pragma unroll
        for (int nt = 0; nt < 2; ++nt)
            acc[mt][nt] = (floatx4){0.f, 0.f, 0.f, 0.f};

    #pragma unroll
    for (int k0 = 0; k0 < 128; k0 += 32) {
        bf16x8 af[4], bfv[2];
        #pragma unroll
        for (int mt = 0; mt < 4; ++mt) {
            uint4 u = *(const uint4*)&At[(mt * 16 + ml) * 136 + k0 + kq * 8];
            af[mt] = __builtin_bit_cast(bf16x8, u);
        }
        #pragma unroll
        for (int nt = 0; nt < 2; ++nt) {
            uint4 u = *(const uint4*)&Bt[(n0w + nt * 16 + ml) * 136 + k0 + kq * 8];
            bfv[nt] = __builtin_bit_cast(bf16x8, u);
        }
        #pragma unroll
        for (int mt = 0; mt < 4; ++mt)
            #pragma unroll
            for (int nt = 0; nt < 2; ++nt)
                acc[mt][nt] = __builtin_amdgcn_mfma_f32_16x16x32_bf16(af[mt], bfv[nt], acc[mt][nt], 0, 0, 0);
    }
    #pragma unroll
    for (int nt = 0; nt < 2; ++nt) {
        int col = n0 + n0w + nt * 16 + ml;
        float bv = bl[col];
        #pragma unroll
        for (int mt = 0; mt < 4; ++mt) {
            int row = m0 + mt * 16 + kq * 4;
            #pragma unroll
            for (int q = 0; q < 4; ++q) {
                int r = row + q;
                if (r < NN) xw[(size_t)r * HE + col] = f2bf(prelu_f(acc[mt][nt][q] + bv, a));
            }
        }
    }
}

// ----------------- per-node attention dots -----------------------------------
__global__ __launch_bounds__(256) void k_dots(const ushort_t* __restrict__ xw,
                                              const float* __restrict__ attl,
                                              float* __restrict__ ddst, float* __restrict__ dsrc) {
    int t = threadIdx.x;
    int lane = t & 63;
    int wid = blockIdx.x * 4 + (t >> 6);
    int nw = gridDim.x * 4;
    int hd = lane >> 4;
    int cm = (lane & 15) * 8;
    float a1[8], a2[8];
    #pragma unroll
    for (int q = 0; q < 8; ++q) {
        a1[q] = attl[hd * 256 + cm + q];
        a2[q] = attl[hd * 256 + 128 + cm + q];
    }
    for (int n = wid; n < NN; n += nw) {
        uint4 u = *(const uint4*)&xw[(size_t)n * HE + lane * 8];
        float v[8] = {bflo(u.x), bfhi(u.x), bflo(u.y), bfhi(u.y),
                      bflo(u.z), bfhi(u.z), bflo(u.w), bfhi(u.w)};
        float p1 = 0.f, p2 = 0.f;
        #pragma unroll
        for (int q = 0; q < 8; ++q) { p1 += v[q] * a1[q]; p2 += v[q] * a2[q]; }
        #pragma unroll
        for (int m = 1; m < 16; m <<= 1) {
            p1 += __shfl_xor(p1, m, 64);
            p2 += __shfl_xor(p2, m, 64);
        }
        if ((lane & 15) == 0) {
            ddst[n * 4 + hd] = p1;
            dsrc[n * 4 + hd] = p2;
        }
    }
}

// ----------------- per-edge raw attention logits (W in 52 bf16 VGPRs) --------
__global__ __launch_bounds__(256) void k_edge(const int* __restrict__ ei, const float* __restrict__ ea,
                                              const ushort_t* __restrict__ eeWb, const float* __restrict__ ebl,
                                              const float* __restrict__ attl, const float* __restrict__ pa,
                                              const float* __restrict__ ddst, const float* __restrict__ dsrc,
                                              float* __restrict__ alpha) {
    int t = threadIdx.x;
    float a = pa[0];
    int lane = t & 63;
    int wid = blockIdx.x * 4 + (t >> 6);
    int nw = gridDim.x * 4;
    int hd = lane >> 4;
    int cm = (lane & 15) * 8;
    int c0 = lane * 8;
    uint4 wreg[DB];
    #pragma unroll
    for (int k = 0; k < DB; ++k)
        wreg[k] = *(const uint4*)&eeWb[k * HE + c0];
    float a2[8], eb[8];
    #pragma unroll
    for (int q = 0; q < 8; ++q) {
        a2[q] = attl[hd * 256 + 128 + cm + q];
        eb[q] = ebl[c0 + q];
    }
    float pself = 0.f;
    #pragma unroll
    for (int q = 0; q < 8; ++q) pself += prelu_f(eb[q], a) * a2[q];
    for (int e = wid; e < NT; e += nw) {
        int s, d;
        float p;
        if (e < NE) {
            s = ei[e]; d = ei[NE + e];
            float eav[DB];
            #pragma unroll
            for (int k = 0; k < DB; ++k) eav[k] = ea[(size_t)e * DB + k];
            float v[8];
            #pragma unroll
            for (int q = 0; q < 8; ++q) v[q] = eb[q];
            #pragma unroll
            for (int k = 0; k < DB; ++k) {
                v[0] += eav[k] * bflo(wreg[k].x); v[1] += eav[k] * bfhi(wreg[k].x);
                v[2] += eav[k] * bflo(wreg[k].y); v[3] += eav[k] * bfhi(wreg[k].y);
                v[4] += eav[k] * bflo(wreg[k].z); v[5] += eav[k] * bfhi(wreg[k].z);
                v[6] += eav[k] * bflo(wreg[k].w); v[7] += eav[k] * bfhi(wreg[k].w);
            }
            p = 0.f;
            #pragma unroll
            for (int q = 0; q < 8; ++q) p += prelu_f(v[q], a) * a2[q];
        } else {
            s = d = e - NE;
            p = pself;
        }
        #pragma unroll
        for (int m = 1; m < 16; m <<= 1) p += __shfl_xor(p, m, 64);
        if ((lane & 15) == 0) {
            float di = ddst[d * 4 + hd];
            float sj = dsrc[s * 4 + hd];
            alpha[e * 4 + hd] = prelu_f(di + sj + p, a);
        }
    }
}

// ----------------- segment softmax over src groups ---------------------------
__global__ void k_softmax(const int* __restrict__ soff, const int* __restrict__ seid,
                          float4* __restrict__ alpha) {
    int n = blockIdx.x * 256 + threadIdx.x;
    if (n >= NN) return;
    int b = soff[n], e = soff[n + 1];
    float mx = -1e30f, my = -1e30f, mz = -1e30f, mw = -1e30f;
    for (int i = b; i < e; ++i) {
        float4 v = alpha[seid[i]];
        mx = fmaxf(mx, v.x); my = fmaxf(my, v.y);
        mz = fmaxf(mz, v.z); mw = fmaxf(mw, v.w);
    }
    float sx = 0.f, sy = 0.f, sz = 0.f, sw = 0.f;
    for (int i = b; i < e; ++i) {
        int id = seid[i];
        float4 v = alpha[id];
        v.x = __expf(v.x - mx); v.y = __expf(v.y - my);
        v.z = __expf(v.z - mz); v.w = __expf(v.w - mw);
        sx += v.x; sy += v.y; sz += v.z; sw += v.w;
        alpha[id] = v;
    }
    sx = 1.f / (sx + 1e-16f); sy = 1.f / (sy + 1e-16f);
    sz = 1.f / (sz + 1e-16f); sw = 1.f / (sw + 1e-16f);
    for (int i = b; i < e; ++i) {
        int id = seid[i];
        float4 v = alpha[id];
        v.x *= sx; v.y *= sy; v.z *= sz; v.w *= sw;
        alpha[id] = v;
    }
}

// ----------------- edge-parallel head-combined messages, atomic scatter ------
// one wave per raw edge (grid-stride, independent iterations). aggr = fp32
// [NN][128]; after xor-16/32 butterfly every lane holds the head-summed value
// for its channel group, so 2 full-exec atomics/edge cover all 128 channels.
__global__ __launch_bounds__(256) void k_msg(const int* __restrict__ ei, const float* __restrict__ ea,
                                             const ushort_t* __restrict__ eeWb, const float* __restrict__ ebl,
                                             const float* __restrict__ pa, const ushort_t* __restrict__ xw,
                                             const float* __restrict__ alpha,
                                             float* __restrict__ aggr) {
    int t = threadIdx.x;
    float a = pa[0];
    int lane = t & 63;
    int wid = blockIdx.x * 4 + (t >> 6);
    int nw = gridDim.x * 4;
    int hd = lane >> 4;
    int c0 = lane * 8;
    uint4 wreg[DB];
    #pragma unroll
    for (int k = 0; k < DB; ++k)
        wreg[k] = *(const uint4*)&eeWb[k * HE + c0];
    float eb[8];
    #pragma unroll
    for (int q = 0; q < 8; ++q) eb[q] = ebl[c0 + q];
    int g = lane >> 4;                     // which v-pair this lane scatters
    int chb = (lane & 15) * 8 + g * 2;     // target channels chb, chb+1
    for (int e = wid; e < NE; e += nw) {
        int src = ei[e];
        int dst = ei[NE + e];
        float4 al4 = *(const float4*)&alpha[e * 4];
        float alv = hd == 0 ? al4.x : hd == 1 ? al4.y : hd == 2 ? al4.z : al4.w;
        float eav[DB];
        #pragma unroll
        for (int k = 0; k < DB; ++k) eav[k] = ea[(size_t)e * DB + k];
        float wv[8];
        #pragma unroll
        for (int q = 0; q < 8; ++q) wv[q] = eb[q];
        #pragma unroll
        for (int k = 0; k < DB; ++k) {
            wv[0] += eav[k] * bflo(wreg[k].x); wv[1] += eav[k] * bfhi(wreg[k].x);
            wv[2] += eav[k] * bflo(wreg[k].y); wv[3] += eav[k] * bfhi(wreg[k].y);
            wv[4] += eav[k] * bflo(wreg[k].z); wv[5] += eav[k] * bfhi(wreg[k].z);
            wv[6] += eav[k] * bflo(wreg[k].w); wv[7] += eav[k] * bfhi(wreg[k].w);
        }
        uint4 u = *(const uint4*)&xw[(size_t)src * HE + c0];
        float v[8] = {bflo(u.x), bfhi(u.x), bflo(u.y), bfhi(u.y),
                      bflo(u.z), bfhi(u.z), bflo(u.w), bfhi(u.w)};
        #pragma unroll
        for (int q = 0; q < 8; ++q) v[q] = (v[q] + prelu_f(wv[q], a)) * alv;
        // head combine: after xor 16/32 every lane has sum over the 4 heads
        #pragma unroll
        for (int q = 0; q < 8; ++q) {
            v[q] += __shfl_xor(v[q], 16, 64);
            v[q] += __shfl_xor(v[q], 32, 64);
        }
        float s0 = g == 0 ? v[0] : g == 1 ? v[2] : g == 2 ? v[4] : v[6];
        float s1 = g == 0 ? v[1] : g == 1 ? v[3] : g == 2 ? v[5] : v[7];
        float* base = &aggr[(size_t)dst * EMB + chb];
        unsafeAtomicAdd(base, s0);
        unsafeAtomicAdd(base + 1, s1);
    }
}

// ----------------- finalize: + self-loop msg, /4, bias, LN (+PReLU) ----------
__global__ __launch_bounds__(256) void k_finalize(const float* __restrict__ aggr, const ushort_t* __restrict__ xw,
                                                  const float* __restrict__ ebl, const float* __restrict__ alpha,
                                                  const float* __restrict__ pa,
                                                  const float* __restrict__ gbias, const float* __restrict__ lng,
                                                  const float* __restrict__ lnb, const float* __restrict__ pgnn,
                                                  int last, ushort_t* __restrict__ hb_out, float* __restrict__ fout) {
    int t = threadIdx.x;
    int lane = t & 63;
    int wid = blockIdx.x * 4 + (t >> 6);
    int nw = gridDim.x * 4;
    float a = pa[0], pg = pgnn[0];
    int ch = lane * 2;
    float ebp0[4], ebp1[4];
    #pragma unroll
    for (int h = 0; h < 4; ++h) {
        ebp0[h] = prelu_f(ebl[h * EMB + ch], a);
        ebp1[h] = prelu_f(ebl[h * EMB + ch + 1], a);
    }
    float gb0 = gbias[ch], gb1 = gbias[ch + 1];
    float g0 = lng[ch], g1 = lng[ch + 1];
    float b0 = lnb[ch], b1 = lnb[ch + 1];
    for (int n = wid; n < NN; n += nw) {
        float2 ag = *(const float2*)&aggr[(size_t)n * EMB + ch];
        float4 al4 = *(const float4*)&alpha[(size_t)(NE + n) * 4];
        float alh[4] = {al4.x, al4.y, al4.z, al4.w};
        float a0 = ag.x, a1 = ag.y;
        #pragma unroll
        for (int h = 0; h < 4; ++h) {
            unsigned u = *(const unsigned*)&xw[(size_t)n * HE + h * EMB + ch];
            a0 += alh[h] * (bflo(u) + ebp0[h]);
            a1 += alh[h] * (bfhi(u) + ebp1[h]);
        }
        a0 = a0 * 0.25f + gb0;
        a1 = a1 * 0.25f + gb1;
        float s8 = a0 + a1, q8 = a0 * a0 + a1 * a1;
        #pragma unroll
        for (int m = 1; m < 64; m <<= 1) {
            s8 += __shfl_xor(s8, m, 64);
            q8 += __shfl_xor(q8, m, 64);
        }
        float mu = s8 * (1.f / 128.f);
        float var = q8 * (1.f / 128.f) - mu * mu;
        float rstd = rsqrtf(var + 1e-5f);
        float o0 = (a0 - mu) * rstd * g0 + b0;
        float o1 = (a1 - mu) * rstd * g1 + b1;
        if (last) {
            *(float2*)&fout[(size_t)n * EMB + ch] = make_float2(o0, o1);
        } else {
            o0 = prelu_f(o0, pg);
            o1 = prelu_f(o1, pg);
            *(unsigned*)&hb_out[(size_t)n * EMB + ch] =
                (unsigned)f2bf(o0) | ((unsigned)f2bf(o1) << 16);
        }
    }
}

extern "C" void kernel_launch(void* const* d_in, const int* in_sizes, int n_in,
                              void* d_out, int out_size, void* d_ws, size_t ws_size,
                              hipStream_t stream) {
    const float* x     = (const float*)d_in[0];
    const int*   ei    = (const int*)d_in[1];      // int32 (JAX x64 disabled)
    const float* ea    = (const float*)d_in[2];
    const float* xembW = (const float*)d_in[3];
    const float* pgnn  = (const float*)d_in[4];
    const float* wlW   = (const float*)d_in[5];
    const float* wlb   = (const float*)d_in[6];
    const float* att   = (const float*)d_in[7];
    const float* gbias = (const float*)d_in[8];
    const float* eeW   = (const float*)d_in[9];
    const float* eeb   = (const float*)d_in[10];
    const float* pgat  = (const float*)d_in[11];
    const float* lng   = (const float*)d_in[12];
    const float* lnb   = (const float*)d_in[13];

    char* w = (char*)d_ws;
    size_t off = 0;
    auto alloc = [&](size_t nbytes) -> char* {
        char* p = w + off;
        off += (nbytes + 255) & ~(size_t)255;
        return p;
    };
    ushort_t* hb    = (ushort_t*)alloc((size_t)NN * EMB * 2);   // 25.6 MB bf16
    ushort_t* xw    = (ushort_t*)alloc((size_t)NN * HE * 2);    // 102.4 MB bf16
    ushort_t* Wtg   = (ushort_t*)alloc((size_t)4 * 512 * 128 * 2);
    ushort_t* eeWb  = (ushort_t*)alloc((size_t)4 * DB * HE * 2);
    float*    ddst  = (float*)alloc((size_t)NN * 4 * 4);
    float*    dsrc  = (float*)alloc((size_t)NN * 4 * 4);
    float*    alpha = (float*)alloc((size_t)NT * 4 * 4);        // 8 MB
    int* scnt = (int*)alloc((size_t)NN * 4);
    int* soff = (int*)alloc((size_t)(NN + 1) * 4);
    int* scur = (int*)alloc((size_t)NN * 4);
    int* seid = (int*)alloc((size_t)NT * 4);
    int* part = (int*)alloc((size_t)NN * 4);
    int* bsum = (int*)alloc(256 * 4);
    float* aggr = (float*)d_out;   // reused as fp32 accumulator each layer

    hipMemsetAsync(scnt, 0, (size_t)NN * 4, stream);
    k_count<<<(NT + 255) / 256, 256, 0, stream>>>(ei, scnt);
    k_scan1<<<196, 512, 0, stream>>>(scnt, part, bsum);
    k_scan2<<<1, 256, 0, stream>>>(bsum, 196);
    k_scan3<<<391, 256, 0, stream>>>(part, bsum, soff, scur);
    k_fill<<<(NT + 255) / 256, 256, 0, stream>>>(ei, scur, seid);
    k_embed<<<2048, 128, 0, stream>>>(x, xembW, pgnn, hb);
    k_prep<<<(4 * 512 * 128 + 255) / 256, 256, 0, stream>>>(wlW, Wtg);
    k_prep_ee<<<(4 * DB * HE + 255) / 256, 256, 0, stream>>>(eeW, eeWb);

    for (int l = 0; l < 4; ++l) {
        const float* bl  = wlb + (size_t)l * HE;
        const float* al  = att + (size_t)l * 1024;
        const ushort_t* eWl = eeWb + (size_t)l * DB * HE;
        const float* ebl = eeb + (size_t)l * HE;
        const float* pa  = pgat + l;
        const ushort_t* Wt = Wtg + (size_t)l * 512 * 128;
        k_gemm<<<dim3((NN + 63) / 64, 4), 256, 0, stream>>>(hb, Wt, bl, pa, xw);
        k_dots<<<2048, 256, 0, stream>>>(xw, al, ddst, dsrc);
        k_edge<<<2048, 256, 0, stream>>>(ei, ea, eWl, ebl, al, pa, ddst, dsrc, alpha);
        k_softmax<<<391, 256, 0, stream>>>(soff, seid, (float4*)alpha);
        hipMemsetAsync(aggr, 0, (size_t)NN * EMB * 4, stream);
        k_msg<<<2048, 256, 0, stream>>>(ei, ea, eWl, ebl, pa, xw, alpha, aggr);
        k_finalize<<<2048, 256, 0, stream>>>(aggr, xw, ebl, alpha, pa,
                                             gbias + (size_t)l * EMB, lng + (size_t)l * EMB,
                                             lnb + (size_t)l * EMB, pgnn, (l == 3) ? 1 : 0,
                                             hb, (float*)d_out);
    }
}